// Round 10
// baseline (42.554 us; speedup 1.0000x reference)
//
#include <hip/hip_runtime.h>

#define HH 56
#define WWID 56
#define HWP (HH*WWID)      // 3136
#define BB 8
#define CC 64
#define NPIX (BB*HWP)      // 25088

// 16-lane-group all-reduce sum, DPP only. All 16 lanes end with the sum.
__device__ __forceinline__ float grp_sum(float x) {
  int xi;
  xi = __builtin_amdgcn_update_dpp(0, __float_as_int(x), 0xB1, 0xF, 0xF, true);  // quad_perm [1,0,3,2]
  x += __int_as_float(xi);
  xi = __builtin_amdgcn_update_dpp(0, __float_as_int(x), 0x4E, 0xF, 0xF, true);  // quad_perm [2,3,0,1]
  x += __int_as_float(xi);
  xi = __builtin_amdgcn_update_dpp(0, __float_as_int(x), 0x141, 0xF, 0xF, true); // row_half_mirror
  x += __int_as_float(xi);
  xi = __builtin_amdgcn_update_dpp(0, __float_as_int(x), 0x140, 0xF, 0xF, true); // row_mirror
  x += __int_as_float(xi);
  return x;
}

__device__ __forceinline__ float dot4(float4 a, float4 b) {
  float t = a.x * b.x;
  t = fmaf(a.y, b.y, t);
  t = fmaf(a.z, b.z, t);
  t = fmaf(a.w, b.w, t);
  return t;
}

// static-index component extract (folds at compile time under full unroll)
__device__ __forceinline__ float fcomp(const float4 v, int i) {
  return i == 0 ? v.x : i == 1 ? v.y : i == 2 ? v.z : v.w;
}

// ---------------- prep: pack w1/w2/w3 to [c/4][o][4], fold conv taps (16 blocks) ----------------
__global__ __launch_bounds__(256) void prep_kernel(
    const float* __restrict__ w1, const float* __restrict__ w2, const float* __restrict__ w3,
    const float* __restrict__ w_fc, const float* __restrict__ w_dep,
    float* __restrict__ w1P, float* __restrict__ w2P, float* __restrict__ w3P,
    float* __restrict__ tab)
{
  const int gt = blockIdx.x * 256 + threadIdx.x;   // 0..4095
  {
    const int idx = gt;
    const int c4 = idx >> 8, r = idx & 255, o = r >> 2, e = r & 3;
    const int c = c4*4 + e;
    w1P[idx] = w1[o*64 + c];
    w2P[idx] = w2[o*64 + c];
    w3P[idx] = w3[o*64 + c];
  }
  if (gt < 27*64) {
    const int d = gt & 63, bt = gt >> 6;
    const int br = bt / 9, tap = bt - br*9;
    float s = 0.f;
    #pragma unroll
    for (int oo = 0; oo < 9; ++oo)
      s += w_dep[d*81 + oo*9 + tap] * w_fc[oo*3 + br];
    tab[gt] = s;
  }
}

// ---------------- qkv: 1x1 convs via LDS-staged x tile, software-pipelined (round-7 proven) ----------------
// block = 256 threads = 32 pixels; lane = output channel o, wave g owns 8 pixels.
// x-tile reads double-buffered at 2-channel granularity; weights prefetched one c4 ahead.
__global__ __launch_bounds__(256) void qkv_kernel(
    const float* __restrict__ x,
    const float* __restrict__ b1, const float* __restrict__ b2, const float* __restrict__ b3,
    const float* __restrict__ w1P, const float* __restrict__ w2P, const float* __restrict__ w3P,
    float* __restrict__ q, float* __restrict__ k, float* __restrict__ v)
{
  __shared__ float xs[64 * 32];     // 8 KB: x[c][px]
  const int tid = threadIdx.x;

  // XCD-chunked swizzle: 784 blocks, 98 per image -> XCD n produces image n
  int bid = (int)blockIdx.x;
  bid = (bid & 7) * 98 + (bid >> 3);

  const int pix0 = bid * 32;
  const int n    = pix0 / HWP;
  const int hw0  = pix0 - n * HWP;
  const float* xb = x + (size_t)n * CC * HWP + hw0;

  // stage x tile: 2048 floats, 2 x float4 per thread, fully coalesced
  #pragma unroll
  for (int r = 0; r < 2; ++r) {
    int idx = r * 256 + tid;        // 0..511
    int c   = idx >> 3;
    int p4  = (idx & 7) * 4;
    *reinterpret_cast<float4*>(&xs[c*32 + p4]) =
        *reinterpret_cast<const float4*>(xb + (size_t)c * HWP + p4);
  }
  __syncthreads();

  const int o = tid & 63;
  const int g = __builtin_amdgcn_readfirstlane((int)(tid >> 6));   // pixel group 0..3
  const float* xg = &xs[g * 8];

  float accq[8], acck[8], accv[8];
  const float bq = b1[o], bk = b2[o], bv = b3[o];
  #pragma unroll
  for (int p = 0; p < 8; ++p) { accq[p] = bq; acck[p] = bk; accv[p] = bv; }

  float4 xbuf[2][4];
  float4 wqb[2], wkb[2], wvb[2];

  // prologue: channels 0,1 and weights for c4=0
  xbuf[0][0] = *reinterpret_cast<const float4*>(xg + 0*32);
  xbuf[0][1] = *reinterpret_cast<const float4*>(xg + 0*32 + 4);
  xbuf[0][2] = *reinterpret_cast<const float4*>(xg + 1*32);
  xbuf[0][3] = *reinterpret_cast<const float4*>(xg + 1*32 + 4);
  wqb[0] = *reinterpret_cast<const float4*>(w1P + o*4);
  wkb[0] = *reinterpret_cast<const float4*>(w2P + o*4);
  wvb[0] = *reinterpret_cast<const float4*>(w3P + o*4);

  #pragma unroll
  for (int ph = 0; ph < 32; ++ph) {          // phase = 2 channels
    const int cur  = ph & 1, nxt = cur ^ 1;
    const int c4   = ph >> 1;
    const int wsel = c4 & 1;
    // prefetch next 2 channels of x
    if (ph < 31) {
      const int cn = (ph + 1) * 2;
      xbuf[nxt][0] = *reinterpret_cast<const float4*>(xg + (cn+0)*32);
      xbuf[nxt][1] = *reinterpret_cast<const float4*>(xg + (cn+0)*32 + 4);
      xbuf[nxt][2] = *reinterpret_cast<const float4*>(xg + (cn+1)*32);
      xbuf[nxt][3] = *reinterpret_cast<const float4*>(xg + (cn+1)*32 + 4);
    }
    // prefetch next c4's weights during the first half of this c4
    if (cur == 0 && c4 < 15) {
      wqb[wsel^1] = *reinterpret_cast<const float4*>(w1P + (c4+1)*256 + o*4);
      wkb[wsel^1] = *reinterpret_cast<const float4*>(w2P + (c4+1)*256 + o*4);
      wvb[wsel^1] = *reinterpret_cast<const float4*>(w3P + (c4+1)*256 + o*4);
    }
    const float wq0 = fcomp(wqb[wsel], cur*2), wq1 = fcomp(wqb[wsel], cur*2+1);
    const float wk0 = fcomp(wkb[wsel], cur*2), wk1 = fcomp(wkb[wsel], cur*2+1);
    const float wv0 = fcomp(wvb[wsel], cur*2), wv1 = fcomp(wvb[wsel], cur*2+1);
    #pragma unroll
    for (int p = 0; p < 8; ++p) {
      const float x0 = (p < 4) ? fcomp(xbuf[cur][0], p) : fcomp(xbuf[cur][1], p-4);
      const float x1 = (p < 4) ? fcomp(xbuf[cur][2], p) : fcomp(xbuf[cur][3], p-4);
      accq[p] = fmaf(wq0, x0, accq[p]);
      acck[p] = fmaf(wk0, x0, acck[p]);
      accv[p] = fmaf(wv0, x0, accv[p]);
      accq[p] = fmaf(wq1, x1, accq[p]);
      acck[p] = fmaf(wk1, x1, acck[p]);
      accv[p] = fmaf(wv1, x1, accv[p]);
    }
  }

  const int pbase = pix0 + g * 8;
  #pragma unroll
  for (int p = 0; p < 8; ++p) {
    size_t off = (size_t)(pbase + p) * 64 + o;   // lanes o consecutive -> 256B stores
    q[off] = accq[p]; k[off] = acck[p]; v[off] = accv[p];
  }
}

// ---------------- fused attention + conv, single pass, exp2 softmax, K+V row double-buffer ----------------
// block = 256 threads = 16 pixels; 16-lane group per pixel, lane holds 4 channels.
// Both K and V rows are prefetched one full window-row ahead (~80 instr of latency cover).
__global__ __launch_bounds__(256) void attn_kernel(
    const float* __restrict__ q, const float* __restrict__ k, const float* __restrict__ v,
    const float* __restrict__ wp, const float* __restrict__ tab,
    const float* __restrict__ b_dep, const float* __restrict__ rate1, const float* __restrict__ rate2,
    float* __restrict__ out)
{
  __shared__ float stab[27 * 64];
  __shared__ float sbd[64];
  __shared__ float sout[64 * 17];

  const int tid  = threadIdx.x;
  for (int i = tid; i < 27*64; i += 256) stab[i] = tab[i];
  if (tid < 64) sbd[tid] = b_dep[tid];
  __syncthreads();

  const int lane = tid & 63;
  const int wid  = __builtin_amdgcn_readfirstlane((int)(tid >> 6));
  const int grp  = lane >> 4;          // group within wave (0..3)
  const int sl   = lane & 15;          // sub-lane = d/4

  // XCD-chunked swizzle: 1568 blocks, 196 per image -> XCD n consumes image n
  int bid = (int)blockIdx.x;
  bid = (bid & 7) * 196 + (bid >> 3);

  const int pixbase = bid * 16;
  const int pl  = wid * 4 + grp;       // local pixel 0..15
  const int pix = pixbase + pl;
  const int n   = pix / HWP;           // uniform per block
  const int hw  = pix - n * HWP;
  const int h   = hw / WWID;
  const int w   = hw - h * WWID;

  const size_t nbase = (size_t)n * HWP * 64;
  const float4 q4 = *reinterpret_cast<const float4*>(q + nbase + (size_t)hw * 64 + sl * 4);

  // reflected coordinates for the 5x5 window
  int hr[5], wr[5];
  #pragma unroll
  for (int i = 0; i < 5; ++i) {
    int t = h + i - 2; hr[i] = t < 0 ? -t : (t >= HH ? 2*HH - 2 - t : t);
    t = w + i - 2;     wr[i] = t < 0 ? -t : (t >= WWID ? 2*WWID - 2 - t : t);
  }

  const float* kb = k + nbase + sl * 4;
  const float* vb = v + nbase + sl * 4;

  // prefetch row-0 K and V (latency hidden under the RPE reductions below)
  float4 ka[5], va[5];
  {
    const size_t rowoff = (size_t)(hr[0] * WWID) * 64;
    const float* krow = kb + rowoff;
    const float* vrow = vb + rowoff;
    #pragma unroll
    for (int j = 0; j < 5; ++j) ka[j] = *reinterpret_cast<const float4*>(krow + wr[j] * 64);
    #pragma unroll
    for (int j = 0; j < 5; ++j) va[j] = *reinterpret_cast<const float4*>(vrow + wr[j] * 64);
  }

  // RPE dots; wp layout [d][2]
  const float4 wa = *reinterpret_cast<const float4*>(wp + 8 * sl);
  const float4 wb = *reinterpret_cast<const float4*>(wp + 8 * sl + 4);
  const float4 wpx4 = {wa.x, wa.z, wb.x, wb.z};
  const float4 wpy4 = {wa.y, wa.w, wb.y, wb.w};
  const float qw0 = grp_sum(dot4(q4, wpx4));
  const float qw1 = grp_sum(dot4(q4, wpy4));

  const float LOG2E = 1.44269504f;
  const float L  = 0.125f * LOG2E;     // logit scale in log2 domain
  const float C  = 2.0f / 55.0f;
  const float A0 = L * qw0 * C;        // coeff for (w - wr)
  const float A1 = L * qw1 * C;        // coeff for (h - hr)

  float s = 0.f;
  float4 oatt = {0.f, 0.f, 0.f, 0.f};
  float4 cacc = {0.f, 0.f, 0.f, 0.f};

  #pragma unroll
  for (int i = 0; i < 5; ++i) {
    // issue next row's K AND V loads before consuming this row's registers
    float4 kn[5], vn[5];
    if (i < 4) {
      const size_t rowoff = (size_t)(hr[i+1] * WWID) * 64;
      const float* krow = kb + rowoff;
      const float* vrow = vb + rowoff;
      #pragma unroll
      for (int j = 0; j < 5; ++j) kn[j] = *reinterpret_cast<const float4*>(krow + wr[j] * 64);
      #pragma unroll
      for (int j = 0; j < 5; ++j) vn[j] = *reinterpret_cast<const float4*>(vrow + wr[j] * 64);
    }

    const float rh = A1 * (float)(h - hr[i]);
    #pragma unroll
    for (int j = 0; j < 5; ++j) {
      const float d16 = grp_sum(dot4(q4, ka[j]));
      const float att = fmaf(L, d16, fmaf(A0, (float)(w - wr[j]), rh));
      const float p = __builtin_exp2f(att);
      s += p;
      oatt.x = fmaf(p, va[j].x, oatt.x);
      oatt.y = fmaf(p, va[j].y, oatt.y);
      oatt.z = fmaf(p, va[j].z, oatt.z);
      oatt.w = fmaf(p, va[j].w, oatt.w);
    }

    // conv branch: taps live in window rows 1..3, cols 1..3 (reuse ka/va regs)
    if (i >= 1 && i <= 3) {
      const int hh = h + i - 2;
      #pragma unroll
      for (int kw = 0; kw < 3; ++kw) {
        const int wc = w + kw - 1;
        const float mk = (((unsigned)hh < HH) && ((unsigned)wc < WWID)) ? 1.f : 0.f;
        const int tap = (i-1)*3 + kw;
        const int j = kw + 1;
        const float4 tq = *reinterpret_cast<const float4*>(&stab[(0*9 + tap)*64 + sl*4]);
        const float4 tk = *reinterpret_cast<const float4*>(&stab[(1*9 + tap)*64 + sl*4]);
        const float4 tv = *reinterpret_cast<const float4*>(&stab[(2*9 + tap)*64 + sl*4]);
        const float4 qn = *reinterpret_cast<const float4*>(q + nbase + (size_t)(hr[i]*WWID + wr[j]) * 64 + sl * 4);
        float sx = tq.x*qn.x; sx = fmaf(tk.x, ka[j].x, sx); sx = fmaf(tv.x, va[j].x, sx);
        float sy = tq.y*qn.y; sy = fmaf(tk.y, ka[j].y, sy); sy = fmaf(tv.y, va[j].y, sy);
        float sz = tq.z*qn.z; sz = fmaf(tk.z, ka[j].z, sz); sz = fmaf(tv.z, va[j].z, sz);
        float sw = tq.w*qn.w; sw = fmaf(tk.w, ka[j].w, sw); sw = fmaf(tv.w, va[j].w, sw);
        cacc.x = fmaf(mk, sx, cacc.x);
        cacc.y = fmaf(mk, sy, cacc.y);
        cacc.z = fmaf(mk, sz, cacc.z);
        cacc.w = fmaf(mk, sw, cacc.w);
      }
    }

    if (i < 4) {
      #pragma unroll
      for (int j = 0; j < 5; ++j) { ka[j] = kn[j]; va[j] = vn[j]; }  // full unroll -> renaming
    }
  }

  const float inv = 1.0f / s;
  const float bdx = sbd[sl*4+0], bdy = sbd[sl*4+1], bdz = sbd[sl*4+2], bdw = sbd[sl*4+3];
  const float r1 = rate1[0] * inv;
  const float r2 = rate2[0];

  float res[4];
  res[0] = r1 * oatt.x + r2 * (cacc.x + bdx);
  res[1] = r1 * oatt.y + r2 * (cacc.y + bdy);
  res[2] = r1 * oatt.z + r2 * (cacc.z + bdz);
  res[3] = r1 * oatt.w + r2 * (cacc.w + bdw);

  // stage to LDS [ch][16 px + pad] then write coalesced float4 per thread
  #pragma unroll
  for (int e = 0; e < 4; ++e)
    sout[(4*sl + e)*17 + pl] = res[e];
  __syncthreads();

  const int c  = tid >> 2;
  const int e4 = (tid & 3) * 4;
  const int hw0 = pixbase - n * HWP;
  float4 o4 = {sout[c*17 + e4 + 0], sout[c*17 + e4 + 1],
               sout[c*17 + e4 + 2], sout[c*17 + e4 + 3]};
  *reinterpret_cast<float4*>(out + ((size_t)(n*64 + c))*HWP + hw0 + e4) = o4;
}

extern "C" void kernel_launch(void* const* d_in, const int* in_sizes, int n_in,
                              void* d_out, int out_size, void* d_ws, size_t ws_size,
                              hipStream_t stream) {
  const float* x     = (const float*)d_in[0];
  const float* w1    = (const float*)d_in[1];
  const float* b1    = (const float*)d_in[2];
  const float* w2    = (const float*)d_in[3];
  const float* b2    = (const float*)d_in[4];
  const float* w3    = (const float*)d_in[5];
  const float* b3    = (const float*)d_in[6];
  const float* wp    = (const float*)d_in[7];
  // d_in[8] = bp : cancels in the RPE difference, unused
  const float* w_fc  = (const float*)d_in[9];
  const float* w_dep = (const float*)d_in[10];
  const float* b_dep = (const float*)d_in[11];
  const float* rate1 = (const float*)d_in[12];
  const float* rate2 = (const float*)d_in[13];
  float* out = (float*)d_out;

  float* ws = (float*)d_ws;
  float* q   = ws;                       // NPIX*64
  float* k   = ws + (size_t)NPIX*64;
  float* v   = ws + (size_t)2*NPIX*64;
  float* w1P = ws + (size_t)3*NPIX*64;   // 4096
  float* w2P = w1P + 4096;
  float* w3P = w2P + 4096;
  float* tab = w3P + 4096;               // 27*64

  prep_kernel<<<16, 256, 0, stream>>>(w1, w2, w3, w_fc, w_dep, w1P, w2P, w3P, tab);
  qkv_kernel<<<NPIX/32, 256, 0, stream>>>(x, b1, b2, b3, w1P, w2P, w3P, q, k, v);
  attn_kernel<<<NPIX/16, 256, 0, stream>>>(q, k, v, wp, tab, b_dep, rate1, rate2, out);
}

// Round 11
// 41.887 us; speedup vs baseline: 1.0159x; 1.0159x over previous
//
#include <hip/hip_runtime.h>

#define HH 56
#define WWID 56
#define HWP (HH*WWID)      // 3136
#define BB 8
#define CC 64
#define NPIX (BB*HWP)      // 25088

// 16-lane-group all-reduce sum, DPP only. All 16 lanes end with the sum.
__device__ __forceinline__ float grp_sum(float x) {
  int xi;
  xi = __builtin_amdgcn_update_dpp(0, __float_as_int(x), 0xB1, 0xF, 0xF, true);  // quad_perm [1,0,3,2]
  x += __int_as_float(xi);
  xi = __builtin_amdgcn_update_dpp(0, __float_as_int(x), 0x4E, 0xF, 0xF, true);  // quad_perm [2,3,0,1]
  x += __int_as_float(xi);
  xi = __builtin_amdgcn_update_dpp(0, __float_as_int(x), 0x141, 0xF, 0xF, true); // row_half_mirror
  x += __int_as_float(xi);
  xi = __builtin_amdgcn_update_dpp(0, __float_as_int(x), 0x140, 0xF, 0xF, true); // row_mirror
  x += __int_as_float(xi);
  return x;
}

__device__ __forceinline__ float dot4(float4 a, float4 b) {
  float t = a.x * b.x;
  t = fmaf(a.y, b.y, t);
  t = fmaf(a.z, b.z, t);
  t = fmaf(a.w, b.w, t);
  return t;
}

// static-index component extract (folds at compile time under full unroll)
__device__ __forceinline__ float fcomp(const float4 v, int i) {
  return i == 0 ? v.x : i == 1 ? v.y : i == 2 ? v.z : v.w;
}

__device__ __forceinline__ int clampi(int v, int lo, int hi) {
  return v < lo ? lo : (v > hi ? hi : v);
}

// ---------------- prep: pack w1/w2/w3 to [c/4][o][4], fold conv taps (16 blocks) ----------------
__global__ __launch_bounds__(256) void prep_kernel(
    const float* __restrict__ w1, const float* __restrict__ w2, const float* __restrict__ w3,
    const float* __restrict__ w_fc, const float* __restrict__ w_dep,
    float* __restrict__ w1P, float* __restrict__ w2P, float* __restrict__ w3P,
    float* __restrict__ tab)
{
  const int gt = blockIdx.x * 256 + threadIdx.x;   // 0..4095
  {
    const int idx = gt;
    const int c4 = idx >> 8, r = idx & 255, o = r >> 2, e = r & 3;
    const int c = c4*4 + e;
    w1P[idx] = w1[o*64 + c];
    w2P[idx] = w2[o*64 + c];
    w3P[idx] = w3[o*64 + c];
  }
  if (gt < 27*64) {
    const int d = gt & 63, bt = gt >> 6;
    const int br = bt / 9, tap = bt - br*9;
    float s = 0.f;
    #pragma unroll
    for (int oo = 0; oo < 9; ++oo)
      s += w_dep[d*81 + oo*9 + tap] * w_fc[oo*3 + br];
    tab[gt] = s;
  }
}

// ---------------- qkv: 1x1 convs via LDS-staged x tile, software-pipelined (round-7 proven) ----------------
__global__ __launch_bounds__(256) void qkv_kernel(
    const float* __restrict__ x,
    const float* __restrict__ b1, const float* __restrict__ b2, const float* __restrict__ b3,
    const float* __restrict__ w1P, const float* __restrict__ w2P, const float* __restrict__ w3P,
    float* __restrict__ q, float* __restrict__ k, float* __restrict__ v)
{
  __shared__ float xs[64 * 32];     // 8 KB: x[c][px]
  const int tid = threadIdx.x;

  // XCD-chunked swizzle: 784 blocks, 98 per image -> XCD n produces image n
  int bid = (int)blockIdx.x;
  bid = (bid & 7) * 98 + (bid >> 3);

  const int pix0 = bid * 32;
  const int n    = pix0 / HWP;
  const int hw0  = pix0 - n * HWP;
  const float* xb = x + (size_t)n * CC * HWP + hw0;

  #pragma unroll
  for (int r = 0; r < 2; ++r) {
    int idx = r * 256 + tid;        // 0..511
    int c   = idx >> 3;
    int p4  = (idx & 7) * 4;
    *reinterpret_cast<float4*>(&xs[c*32 + p4]) =
        *reinterpret_cast<const float4*>(xb + (size_t)c * HWP + p4);
  }
  __syncthreads();

  const int o = tid & 63;
  const int g = __builtin_amdgcn_readfirstlane((int)(tid >> 6));   // pixel group 0..3
  const float* xg = &xs[g * 8];

  float accq[8], acck[8], accv[8];
  const float bq = b1[o], bk = b2[o], bv = b3[o];
  #pragma unroll
  for (int p = 0; p < 8; ++p) { accq[p] = bq; acck[p] = bk; accv[p] = bv; }

  float4 xbuf[2][4];
  float4 wqb[2], wkb[2], wvb[2];

  xbuf[0][0] = *reinterpret_cast<const float4*>(xg + 0*32);
  xbuf[0][1] = *reinterpret_cast<const float4*>(xg + 0*32 + 4);
  xbuf[0][2] = *reinterpret_cast<const float4*>(xg + 1*32);
  xbuf[0][3] = *reinterpret_cast<const float4*>(xg + 1*32 + 4);
  wqb[0] = *reinterpret_cast<const float4*>(w1P + o*4);
  wkb[0] = *reinterpret_cast<const float4*>(w2P + o*4);
  wvb[0] = *reinterpret_cast<const float4*>(w3P + o*4);

  #pragma unroll
  for (int ph = 0; ph < 32; ++ph) {          // phase = 2 channels
    const int cur  = ph & 1, nxt = cur ^ 1;
    const int c4   = ph >> 1;
    const int wsel = c4 & 1;
    if (ph < 31) {
      const int cn = (ph + 1) * 2;
      xbuf[nxt][0] = *reinterpret_cast<const float4*>(xg + (cn+0)*32);
      xbuf[nxt][1] = *reinterpret_cast<const float4*>(xg + (cn+0)*32 + 4);
      xbuf[nxt][2] = *reinterpret_cast<const float4*>(xg + (cn+1)*32);
      xbuf[nxt][3] = *reinterpret_cast<const float4*>(xg + (cn+1)*32 + 4);
    }
    if (cur == 0 && c4 < 15) {
      wqb[wsel^1] = *reinterpret_cast<const float4*>(w1P + (c4+1)*256 + o*4);
      wkb[wsel^1] = *reinterpret_cast<const float4*>(w2P + (c4+1)*256 + o*4);
      wvb[wsel^1] = *reinterpret_cast<const float4*>(w3P + (c4+1)*256 + o*4);
    }
    const float wq0 = fcomp(wqb[wsel], cur*2), wq1 = fcomp(wqb[wsel], cur*2+1);
    const float wk0 = fcomp(wkb[wsel], cur*2), wk1 = fcomp(wkb[wsel], cur*2+1);
    const float wv0 = fcomp(wvb[wsel], cur*2), wv1 = fcomp(wvb[wsel], cur*2+1);
    #pragma unroll
    for (int p = 0; p < 8; ++p) {
      const float x0 = (p < 4) ? fcomp(xbuf[cur][0], p) : fcomp(xbuf[cur][1], p-4);
      const float x1 = (p < 4) ? fcomp(xbuf[cur][2], p) : fcomp(xbuf[cur][3], p-4);
      accq[p] = fmaf(wq0, x0, accq[p]);
      acck[p] = fmaf(wk0, x0, acck[p]);
      accv[p] = fmaf(wv0, x0, accv[p]);
      accq[p] = fmaf(wq1, x1, accq[p]);
      acck[p] = fmaf(wk1, x1, acck[p]);
      accv[p] = fmaf(wv1, x1, accv[p]);
    }
  }

  const int pbase = pix0 + g * 8;
  #pragma unroll
  for (int p = 0; p < 8; ++p) {
    size_t off = (size_t)(pbase + p) * 64 + o;   // lanes o consecutive -> 256B stores
    q[off] = accq[p]; k[off] = acck[p]; v[off] = accv[p];
  }
}

// ---------------- fused attention + conv over a 4x4 pixel tile, K/V/q window union in LDS ----------------
// block = 256 threads = 16 groups of 16 lanes; group = one pixel of the 4x4 patch; lane holds 4 ch.
// K/V staged for the 8x8 union (rows/cols t0-2..t0+5 clamped; reflected coords always land inside),
// q staged for the 6x6 conv halo. All window reads become LDS reads; global traffic cut ~5.6x.
__global__ __launch_bounds__(256) void attn_kernel(
    const float* __restrict__ q, const float* __restrict__ k, const float* __restrict__ v,
    const float* __restrict__ wp, const float* __restrict__ tab,
    const float* __restrict__ b_dep, const float* __restrict__ rate1, const float* __restrict__ rate2,
    float* __restrict__ out)
{
  __shared__ float kt[64 * 64];     // [pos=r*8+c][64ch]  16 KB
  __shared__ float vt[64 * 64];     // 16 KB
  __shared__ float qt[36 * 64];     // [pos=r*6+c][64ch]  9 KB (rows t0-1..t0+4, cols c0-1..c0+4)
  __shared__ float sout[64 * 17];

  const int tid = threadIdx.x;

  // XCD-chunked swizzle: 1568 blocks = 8 images x 196 tiles -> XCD n consumes image n
  const int raw = (int)blockIdx.x;
  const int n   = raw & 7;
  const int t   = raw >> 3;            // 0..195
  const int tr  = t / 14;
  const int tc  = t - tr * 14;
  const int t0  = tr * 4;              // patch top row
  const int c0  = tc * 4;              // patch left col

  const size_t nbase = (size_t)n * HWP * 64;

  // ---- stage K and V 8x8 union (clamped coords) ----
  #pragma unroll
  for (int rep = 0; rep < 4; ++rep) {
    const int idx = rep * 256 + tid;         // 0..1023
    const int pos = idx >> 4;                // 0..63
    const int f   = (idx & 15) * 4;          // float offset within 64ch
    const int r   = pos >> 3, c = pos & 7;
    const int gr  = clampi(t0 - 2 + r, 0, HH - 1);
    const int gc  = clampi(c0 - 2 + c, 0, WWID - 1);
    const size_t src = nbase + (size_t)(gr * WWID + gc) * 64 + f;
    *reinterpret_cast<float4*>(&kt[pos * 64 + f]) = *reinterpret_cast<const float4*>(k + src);
    *reinterpret_cast<float4*>(&vt[pos * 64 + f]) = *reinterpret_cast<const float4*>(v + src);
  }
  // ---- stage q 6x6 halo ----
  #pragma unroll
  for (int rep = 0; rep < 3; ++rep) {
    const int idx = rep * 256 + tid;         // 0..767
    if (idx < 576) {
      const int pos = idx >> 4;              // 0..35
      const int f   = (idx & 15) * 4;
      const int r   = pos / 6, c = pos - r * 6;
      const int gr  = clampi(t0 - 1 + r, 0, HH - 1);
      const int gc  = clampi(c0 - 1 + c, 0, WWID - 1);
      *reinterpret_cast<float4*>(&qt[pos * 64 + f]) =
          *reinterpret_cast<const float4*>(q + nbase + (size_t)(gr * WWID + gc) * 64 + f);
    }
  }
  __syncthreads();

  const int group = tid >> 4;          // 0..15 = pixel in patch
  const int sl    = tid & 15;          // sub-lane = d/4
  const int pr    = group >> 2;
  const int pc    = group & 3;
  const int h     = t0 + pr;
  const int w     = c0 + pc;

  const float4 q4 = *reinterpret_cast<const float4*>(&qt[((pr + 1) * 6 + (pc + 1)) * 64 + sl * 4]);

  // reflected coords, tile-local indices (always within the staged 8x8)
  int kr[5], kc[5], hrg[5], wrg[5];
  #pragma unroll
  for (int i = 0; i < 5; ++i) {
    int tt = h + i - 2; hrg[i] = tt < 0 ? -tt : (tt >= HH ? 2*HH - 2 - tt : tt);
    kr[i] = hrg[i] - t0 + 2;
    tt = w + i - 2;     wrg[i] = tt < 0 ? -tt : (tt >= WWID ? 2*WWID - 2 - tt : tt);
    kc[i] = wrg[i] - c0 + 2;
  }

  // prefetch row-0 K and V from LDS (latency hidden under the RPE reductions)
  float4 ka[5], va[5];
  #pragma unroll
  for (int j = 0; j < 5; ++j) {
    const int p0 = (kr[0] * 8 + kc[j]) * 64 + sl * 4;
    ka[j] = *reinterpret_cast<const float4*>(&kt[p0]);
    va[j] = *reinterpret_cast<const float4*>(&vt[p0]);
  }

  // RPE dots; wp layout [d][2]
  const float4 wa = *reinterpret_cast<const float4*>(wp + 8 * sl);
  const float4 wb = *reinterpret_cast<const float4*>(wp + 8 * sl + 4);
  const float4 wpx4 = {wa.x, wa.z, wb.x, wb.z};
  const float4 wpy4 = {wa.y, wa.w, wb.y, wb.w};
  const float qw0 = grp_sum(dot4(q4, wpx4));
  const float qw1 = grp_sum(dot4(q4, wpy4));

  const float LOG2E = 1.44269504f;
  const float L  = 0.125f * LOG2E;
  const float C  = 2.0f / 55.0f;
  const float A0 = L * qw0 * C;
  const float A1 = L * qw1 * C;

  float s = 0.f;
  float4 oatt = {0.f, 0.f, 0.f, 0.f};
  float4 cacc = {0.f, 0.f, 0.f, 0.f};

  #pragma unroll
  for (int i = 0; i < 5; ++i) {
    // prefetch next row's K/V from LDS before consuming this row
    float4 kn[5], vn[5];
    if (i < 4) {
      #pragma unroll
      for (int j = 0; j < 5; ++j) {
        const int p1 = (kr[i+1] * 8 + kc[j]) * 64 + sl * 4;
        kn[j] = *reinterpret_cast<const float4*>(&kt[p1]);
        vn[j] = *reinterpret_cast<const float4*>(&vt[p1]);
      }
    }

    const float rh = A1 * (float)(h - hrg[i]);
    #pragma unroll
    for (int j = 0; j < 5; ++j) {
      const float d16 = grp_sum(dot4(q4, ka[j]));
      const float att = fmaf(L, d16, fmaf(A0, (float)(w - wrg[j]), rh));
      const float p = __builtin_exp2f(att);
      s += p;
      oatt.x = fmaf(p, va[j].x, oatt.x);
      oatt.y = fmaf(p, va[j].y, oatt.y);
      oatt.z = fmaf(p, va[j].z, oatt.z);
      oatt.w = fmaf(p, va[j].w, oatt.w);
    }

    // conv branch: taps = window rows 1..3, cols 1..3 (reuse ka/va; q from LDS halo)
    if (i >= 1 && i <= 3) {
      const int kh = i - 1;
      const int hh = h + kh - 1;
      #pragma unroll
      for (int kw = 0; kw < 3; ++kw) {
        const int wc = w + kw - 1;
        const float mk = (((unsigned)hh < HH) && ((unsigned)wc < WWID)) ? 1.f : 0.f;
        const int tap = kh*3 + kw;
        const int j = kw + 1;
        const float4 tq = *reinterpret_cast<const float4*>(tab + (0*9 + tap)*64 + sl*4);
        const float4 tk = *reinterpret_cast<const float4*>(tab + (1*9 + tap)*64 + sl*4);
        const float4 tv = *reinterpret_cast<const float4*>(tab + (2*9 + tap)*64 + sl*4);
        const float4 qn = *reinterpret_cast<const float4*>(&qt[((pr + kh) * 6 + (pc + kw)) * 64 + sl * 4]);
        float sx = tq.x*qn.x; sx = fmaf(tk.x, ka[j].x, sx); sx = fmaf(tv.x, va[j].x, sx);
        float sy = tq.y*qn.y; sy = fmaf(tk.y, ka[j].y, sy); sy = fmaf(tv.y, va[j].y, sy);
        float sz = tq.z*qn.z; sz = fmaf(tk.z, ka[j].z, sz); sz = fmaf(tv.z, va[j].z, sz);
        float sw = tq.w*qn.w; sw = fmaf(tk.w, ka[j].w, sw); sw = fmaf(tv.w, va[j].w, sw);
        cacc.x = fmaf(mk, sx, cacc.x);
        cacc.y = fmaf(mk, sy, cacc.y);
        cacc.z = fmaf(mk, sz, cacc.z);
        cacc.w = fmaf(mk, sw, cacc.w);
      }
    }

    if (i < 4) {
      #pragma unroll
      for (int j = 0; j < 5; ++j) { ka[j] = kn[j]; va[j] = vn[j]; }
    }
  }

  const float inv = 1.0f / s;
  const float4 bd = *reinterpret_cast<const float4*>(b_dep + sl * 4);
  const float r1 = rate1[0] * inv;
  const float r2 = rate2[0];

  float res[4];
  res[0] = r1 * oatt.x + r2 * (cacc.x + bd.x);
  res[1] = r1 * oatt.y + r2 * (cacc.y + bd.y);
  res[2] = r1 * oatt.z + r2 * (cacc.z + bd.z);
  res[3] = r1 * oatt.w + r2 * (cacc.w + bd.w);

  // stage to LDS [ch][16 px + pad], then one float4 row-store per thread
  #pragma unroll
  for (int e = 0; e < 4; ++e)
    sout[(4*sl + e)*17 + group] = res[e];
  __syncthreads();

  const int cc  = tid >> 2;          // channel 0..63
  const int pr2 = tid & 3;           // patch row
  float4 o4 = {sout[cc*17 + pr2*4 + 0], sout[cc*17 + pr2*4 + 1],
               sout[cc*17 + pr2*4 + 2], sout[cc*17 + pr2*4 + 3]};
  *reinterpret_cast<float4*>(out + ((size_t)(n*64 + cc))*HWP + (t0 + pr2)*WWID + c0) = o4;
}

extern "C" void kernel_launch(void* const* d_in, const int* in_sizes, int n_in,
                              void* d_out, int out_size, void* d_ws, size_t ws_size,
                              hipStream_t stream) {
  const float* x     = (const float*)d_in[0];
  const float* w1    = (const float*)d_in[1];
  const float* b1    = (const float*)d_in[2];
  const float* w2    = (const float*)d_in[3];
  const float* b2    = (const float*)d_in[4];
  const float* w3    = (const float*)d_in[5];
  const float* b3    = (const float*)d_in[6];
  const float* wp    = (const float*)d_in[7];
  // d_in[8] = bp : cancels in the RPE difference, unused
  const float* w_fc  = (const float*)d_in[9];
  const float* w_dep = (const float*)d_in[10];
  const float* b_dep = (const float*)d_in[11];
  const float* rate1 = (const float*)d_in[12];
  const float* rate2 = (const float*)d_in[13];
  float* out = (float*)d_out;

  float* ws = (float*)d_ws;
  float* q   = ws;                       // NPIX*64
  float* k   = ws + (size_t)NPIX*64;
  float* v   = ws + (size_t)2*NPIX*64;
  float* w1P = ws + (size_t)3*NPIX*64;   // 4096
  float* w2P = w1P + 4096;
  float* w3P = w2P + 4096;
  float* tab = w3P + 4096;               // 27*64

  prep_kernel<<<16, 256, 0, stream>>>(w1, w2, w3, w_fc, w_dep, w1P, w2P, w3P, tab);
  qkv_kernel<<<NPIX/32, 256, 0, stream>>>(x, b1, b2, b3, w1P, w2P, w3P, q, k, v);
  attn_kernel<<<NPIX/16, 256, 0, stream>>>(q, k, v, wp, tab, b_dep, rate1, rate2, out);
}